// Round 1
// baseline (512.427 us; speedup 1.0000x reference)
//
#include <hip/hip_runtime.h>
#include <math.h>

#define H_ 128
#define W_ 128
#define C_ 64
#define O_ 64
#define B_ 8
#define K2_ 9
#define HWSZ (H_*W_)

// ---------------------------------------------------------------------------
// Kernel T: transpose w (O,C,3,3) -> wt (K2, C, O) so the sample-GEMM reads
// weights contiguously in o (wave-uniform -> s_load_dwordx8/16).
// ---------------------------------------------------------------------------
__global__ __launch_bounds__(256) void transpose_w_k(const float* __restrict__ w,
                                                     float* __restrict__ wt) {
    int id = blockIdx.x * 256 + threadIdx.x;   // k*C*O + c*O + o
    if (id >= K2_ * C_ * O_) return;
    int o = id & (O_ - 1);
    int c = (id >> 6) & (C_ - 1);
    int k = id / (C_ * O_);
    wt[id] = w[(o * C_ + c) * K2_ + k];
}

// ---------------------------------------------------------------------------
// Kernel A: 3x3 conv producing 18 offset + 9 mask channels per pixel.
// Emits sampling coords py/px and mask directly (fused reshape + coord calc).
// One thread per pixel; weights are wave-uniform -> scalar loads.
// ---------------------------------------------------------------------------
__global__ __launch_bounds__(256) void conv_offmask_k(
    const float* __restrict__ x,
    const float* __restrict__ w_off, const float* __restrict__ b_off,
    const float* __restrict__ w_mod, const float* __restrict__ b_mod,
    float* __restrict__ pyA, float* __restrict__ pxA, float* __restrict__ mA) {
    int id = blockIdx.x * 256 + threadIdx.x;     // b*H*W + h*W + w
    int w = id & (W_ - 1);
    int h = (id >> 7) & (H_ - 1);
    int b = id >> 14;

    int offs[9];
    float valid[9];
#pragma unroll
    for (int i = 0; i < 9; i++) {
        int dy = i / 3 - 1, dx = i % 3 - 1;
        int yy = h + dy, xx = w + dx;
        bool v = (yy >= 0 && yy < H_ && xx >= 0 && xx < W_);
        int yc = min(max(yy, 0), H_ - 1);
        int xc = min(max(xx, 0), W_ - 1);
        offs[i] = yc * W_ + xc;
        valid[i] = v ? 1.0f : 0.0f;
    }

    float acc[27];
#pragma unroll
    for (int o = 0; o < 27; o++) acc[o] = 0.0f;

    const float* xb = x + b * (C_ * HWSZ);
    for (int c = 0; c < C_; c++) {
        const float* xc = xb + c * HWSZ;
        float v[9];
#pragma unroll
        for (int i = 0; i < 9; i++) v[i] = xc[offs[i]] * valid[i];
        const float* wo = w_off + c * 9;
#pragma unroll
        for (int o = 0; o < 18; o++) {
#pragma unroll
            for (int k = 0; k < 9; k++) acc[o] += v[k] * wo[o * (C_ * 9) + k];
        }
        const float* wm = w_mod + c * 9;
#pragma unroll
        for (int o = 0; o < 9; o++) {
#pragma unroll
            for (int k = 0; k < 9; k++) acc[18 + o] += v[k] * wm[o * (C_ * 9) + k];
        }
    }

#pragma unroll
    for (int k = 0; k < 9; k++) {
        float dy = acc[2 * k] + b_off[2 * k];
        float dx = acc[2 * k + 1] + b_off[2 * k + 1];
        float mm = acc[18 + k] + b_mod[k];
        float mask = 2.0f / (1.0f + expf(-mm));
        float py = dy + (float)h - 1.0f + (float)(k / 3);
        float px = dx + (float)w - 1.0f + (float)(k % 3);
        int idx = ((b * 9 + k) * H_ + h) * W_ + w;
        pyA[idx] = py;
        pxA[idx] = px;
        mA[idx] = mask;
    }
}

// ---------------------------------------------------------------------------
// Kernel B: bilinear sample + masked reduction GEMM.
// One thread per pixel, all 64 output channels accumulated in registers.
// Bilinear weights computed once per (pixel,k); shared across 64 channels.
// Weight reads are wave-uniform contiguous (s_load); stores coalesced.
// ---------------------------------------------------------------------------
__global__ __launch_bounds__(256) void sample_gemm_k(
    const float* __restrict__ x,
    const float* __restrict__ pyA, const float* __restrict__ pxA,
    const float* __restrict__ mA, const float* __restrict__ wt,
    const float* __restrict__ bias, float* __restrict__ out) {
    int id = blockIdx.x * 256 + threadIdx.x;
    int w = id & (W_ - 1);
    int h = (id >> 7) & (H_ - 1);
    int b = id >> 14;

    float acc[O_];
#pragma unroll
    for (int o = 0; o < O_; o++) acc[o] = 0.0f;

    const float* xb = x + b * (C_ * HWSZ);

    for (int k = 0; k < 9; k++) {
        int idx = ((b * 9 + k) * H_ + h) * W_ + w;
        float py = pyA[idx];
        float px = pxA[idx];
        float m = mA[idx];

        float y0f = floorf(py), x0f = floorf(px);
        float wy = py - y0f, wx = px - x0f;
        int y0 = (int)y0f, x0 = (int)x0f;
        int y1 = y0 + 1, x1 = x0 + 1;
        float vy0 = (y0 >= 0 && y0 < H_) ? 1.0f : 0.0f;
        float vy1 = (y1 >= 0 && y1 < H_) ? 1.0f : 0.0f;
        float vx0 = (x0 >= 0 && x0 < W_) ? 1.0f : 0.0f;
        float vx1 = (x1 >= 0 && x1 < W_) ? 1.0f : 0.0f;
        int y0c = min(max(y0, 0), H_ - 1), y1c = min(max(y1, 0), H_ - 1);
        int x0c = min(max(x0, 0), W_ - 1), x1c = min(max(x1, 0), W_ - 1);

        float w00 = (1.0f - wy) * (1.0f - wx) * vy0 * vx0 * m;
        float w01 = (1.0f - wy) * wx * vy0 * vx1 * m;
        float w10 = wy * (1.0f - wx) * vy1 * vx0 * m;
        float w11 = wy * wx * vy1 * vx1 * m;

        int o00 = y0c * W_ + x0c, o01 = y0c * W_ + x1c;
        int o10 = y1c * W_ + x0c, o11 = y1c * W_ + x1c;

        const float* wp = wt + k * (C_ * O_);
        for (int c = 0; c < C_; c++) {
            const float* xc = xb + c * HWSZ;
            float s = w00 * xc[o00] + w01 * xc[o01] + w10 * xc[o10] + w11 * xc[o11];
            const float* wpc = wp + c * O_;
#pragma unroll
            for (int o = 0; o < O_; o++) acc[o] += s * wpc[o];
        }
    }

    int obase = (b * O_) * HWSZ + h * W_ + w;
#pragma unroll
    for (int o = 0; o < O_; o++) out[obase + o * HWSZ] = acc[o] + bias[o];
}

// ---------------------------------------------------------------------------
extern "C" void kernel_launch(void* const* d_in, const int* in_sizes, int n_in,
                              void* d_out, int out_size, void* d_ws, size_t ws_size,
                              hipStream_t stream) {
    const float* x     = (const float*)d_in[0];
    const float* w_off = (const float*)d_in[1];
    const float* b_off = (const float*)d_in[2];
    const float* w_mod = (const float*)d_in[3];
    const float* b_mod = (const float*)d_in[4];
    const float* w     = (const float*)d_in[5];
    const float* bias  = (const float*)d_in[6];
    float* out = (float*)d_out;

    const int nCoord = B_ * K2_ * HWSZ;   // 1,179,648
    float* pyA = (float*)d_ws;
    float* pxA = pyA + nCoord;
    float* mA  = pxA + nCoord;
    float* wt  = mA + nCoord;             // 36,864 floats

    int npix = B_ * HWSZ;                 // 131,072

    hipLaunchKernelGGL(transpose_w_k, dim3((K2_ * C_ * O_ + 255) / 256), dim3(256),
                       0, stream, w, wt);
    hipLaunchKernelGGL(conv_offmask_k, dim3(npix / 256), dim3(256), 0, stream,
                       x, w_off, b_off, w_mod, b_mod, pyA, pxA, mA);
    hipLaunchKernelGGL(sample_gemm_k, dim3(npix / 256), dim3(256), 0, stream,
                       x, pyA, pxA, mA, wt, bias, out);
}